// Round 2
// baseline (424.875 us; speedup 1.0000x reference)
//
#include <hip/hip_runtime.h>
#include <hip/hip_cooperative_groups.h>

namespace cg = cooperative_groups;

#define Q 4096
#define L 8192
#define NBLK 1024

// One fused cooperative kernel:
//  A  : score[l] = ctx[l].q                  (reads ctx from HBM, 128 MiB)
//  B  : softmax stats (redundant per block, score is tiny & L2-hot)
//  C  : partial weighted sums of ctx rows    (ctx now LLC-resident)  [blocks 0..511]
//  C2 : out1[i] = Kw[i,0:Q].q                (HBM stream, overlaps C) [blocks 512..1023]
//  D1 : s_t = reduce partials
//  D  : out[i] = out1[i] + Kw[i,Q:2Q].s_t    (second half of Kw from HBM)
__global__ __launch_bounds__(256, 4) void fused_attn(
    const float* __restrict__ qvec, const float* __restrict__ ctx,
    const float* __restrict__ Kw, float* __restrict__ out,
    float* __restrict__ score, float* __restrict__ out1,
    float* __restrict__ s_t, float* __restrict__ partial)
{
    cg::grid_group grid = cg::this_grid();
    const int tid  = threadIdx.x;
    const int lane = tid & 63;
    const int wid  = tid >> 6;
    const int gw   = blockIdx.x * 4 + wid;          // global wave id 0..4095

    const float4* __restrict__ qv = (const float4*)qvec;

    // ---------------- Phase A: scores (2 rows per wave) ----------------
    for (int rr = 0; rr < 2; ++rr) {
        const int l = gw + rr * 4096;
        const float4* __restrict__ row = (const float4*)(ctx + (size_t)l * Q);
        float acc = 0.f;
        #pragma unroll 4
        for (int it = 0; it < 16; ++it) {
            const int idx = it * 64 + lane;
            float4 a = row[idx], b = qv[idx];
            acc = fmaf(a.x, b.x, acc); acc = fmaf(a.y, b.y, acc);
            acc = fmaf(a.z, b.z, acc); acc = fmaf(a.w, b.w, acc);
        }
        #pragma unroll
        for (int off = 32; off > 0; off >>= 1) acc += __shfl_down(acc, off, 64);
        if (lane == 0) score[l] = acc;
    }

    grid.sync();

    // ------- Phase B + C (blocks 0..511)  ||  Phase C2 (blocks 512..1023) -------
    __shared__ float red[4];
    __shared__ float att_s[64];
    if (blockIdx.x < 512) {
        // softmax stats, redundant per block (score[] is 32 KB, L2-hot)
        float lm = -3.4e38f;
        for (int i = tid; i < L; i += 256) lm = fmaxf(lm, score[i]);
        #pragma unroll
        for (int off = 32; off > 0; off >>= 1) lm = fmaxf(lm, __shfl_down(lm, off, 64));
        if (lane == 0) red[wid] = lm;
        __syncthreads();
        const float m = fmaxf(fmaxf(red[0], red[1]), fmaxf(red[2], red[3]));
        __syncthreads();
        float ls = 0.f;
        for (int i = tid; i < L; i += 256) ls += __expf(score[i] - m);
        #pragma unroll
        for (int off = 32; off > 0; off >>= 1) ls += __shfl_down(ls, off, 64);
        if (lane == 0) red[wid] = ls;
        __syncthreads();
        const float inv = 1.f / (red[0] + red[1] + red[2] + red[3]);

        // weighted-sum partial: block = rc (row-chunk of 64) x cq (1024-col chunk)
        const int cq = blockIdx.x & 3;
        const int rc = blockIdx.x >> 2;       // 0..127
        const int r0 = rc * 64;
        if (tid < 64) att_s[tid] = __expf(score[r0 + tid] - m) * inv;
        __syncthreads();

        const int col4 = cq * 256 + tid;      // float4 column index
        float4 acc = make_float4(0.f, 0.f, 0.f, 0.f);
        #pragma unroll 4
        for (int r = 0; r < 64; ++r) {
            const float a = att_s[r];
            float4 v = ((const float4*)ctx)[(size_t)(r0 + r) * (Q / 4) + col4];
            acc.x = fmaf(a, v.x, acc.x); acc.y = fmaf(a, v.y, acc.y);
            acc.z = fmaf(a, v.z, acc.z); acc.w = fmaf(a, v.w, acc.w);
        }
        ((float4*)partial)[(size_t)rc * (Q / 4) + col4] = acc;
    } else {
        // out1[i] = Kw[i, 0:Q] . q   (2 rows per wave)
        const int gw2 = (blockIdx.x - 512) * 4 + wid;   // 0..2047
        for (int rr = 0; rr < 2; ++rr) {
            const int i = gw2 + rr * 2048;
            const float4* __restrict__ row = (const float4*)(Kw + (size_t)i * (2 * Q));
            float acc = 0.f;
            #pragma unroll 4
            for (int it = 0; it < 16; ++it) {
                const int idx = it * 64 + lane;
                float4 a = row[idx], b = qv[idx];
                acc = fmaf(a.x, b.x, acc); acc = fmaf(a.y, b.y, acc);
                acc = fmaf(a.z, b.z, acc); acc = fmaf(a.w, b.w, acc);
            }
            #pragma unroll
            for (int off = 32; off > 0; off >>= 1) acc += __shfl_down(acc, off, 64);
            if (lane == 0) out1[i] = acc;
        }
    }

    grid.sync();

    // ---------------- Phase D1: s_t = reduce partials (waves 0..1023) ----------
    if (gw < Q / 4) {
        const float4* __restrict__ p = (const float4*)partial;
        float4 acc = make_float4(0.f, 0.f, 0.f, 0.f);
        #pragma unroll
        for (int rc = lane; rc < 128; rc += 64) {
            float4 v = p[(size_t)rc * (Q / 4) + gw];
            acc.x += v.x; acc.y += v.y; acc.z += v.z; acc.w += v.w;
        }
        #pragma unroll
        for (int off = 32; off > 0; off >>= 1) {
            acc.x += __shfl_down(acc.x, off, 64);
            acc.y += __shfl_down(acc.y, off, 64);
            acc.z += __shfl_down(acc.z, off, 64);
            acc.w += __shfl_down(acc.w, off, 64);
        }
        if (lane == 0) ((float4*)s_t)[gw] = acc;
    }

    grid.sync();

    // ---------------- Phase D: out[i] = out1[i] + Kw[i, Q:2Q] . s_t ------------
    {
        const int i = gw;   // 4096 waves <-> 4096 output rows
        const float4* __restrict__ row = (const float4*)(Kw + (size_t)i * (2 * Q) + Q);
        const float4* __restrict__ sv  = (const float4*)s_t;
        float acc = 0.f;
        #pragma unroll 4
        for (int it = 0; it < 16; ++it) {
            const int idx = it * 64 + lane;
            float4 a = row[idx], b = sv[idx];
            acc = fmaf(a.x, b.x, acc); acc = fmaf(a.y, b.y, acc);
            acc = fmaf(a.z, b.z, acc); acc = fmaf(a.w, b.w, acc);
        }
        #pragma unroll
        for (int off = 32; off > 0; off >>= 1) acc += __shfl_down(acc, off, 64);
        if (lane == 0) out[i] = out1[i] + acc;
    }
}

// ---------------------------------------------------------------------------
extern "C" void kernel_launch(void* const* d_in, const int* in_sizes, int n_in,
                              void* d_out, int out_size, void* d_ws, size_t ws_size,
                              hipStream_t stream)
{
    const float* query = (const float*)d_in[0];   // [Q]
    const float* ctx   = (const float*)d_in[1];   // [L, Q]
    const float* Kw    = (const float*)d_in[2];   // [Q, 2Q]
    float* out = (float*)d_out;                   // [Q]

    // workspace layout (floats)
    float* ws      = (float*)d_ws;
    float* score   = ws;                      // 8192
    float* out1    = ws + L;                  // 4096
    float* s_t     = ws + L + Q;              // 4096
    float* partial = ws + L + 2 * Q;          // 128 * 4096 = 524288 (2 MiB)

    void* args[] = {(void*)&query, (void*)&ctx, (void*)&Kw, (void*)&out,
                    (void*)&score, (void*)&out1, (void*)&s_t, (void*)&partial};
    hipLaunchCooperativeKernel((const void*)fused_attn, dim3(NBLK), dim3(256),
                               args, 0, stream);
}

// Round 3
// 71.090 us; speedup vs baseline: 5.9766x; 5.9766x over previous
//
#include <hip/hip_runtime.h>

#define Q 4096
#define L 8192
#define NCB 1024               // ctx blocks in K1
#define RPB (L / NCB)          // 8 rows per ctx block
#define NOB 256                // out1 blocks in K1 (4 waves each, 4 rows/wave)

// ---------------------------------------------------------------------------
// K1a (blocks 0..NCB-1): online softmax-weighted sum over 8 ctx rows.
//      Row is loaded once into registers: used for the score dot AND the
//      weighted accumulation. Emits partial[b][Q], m_arr[b], Z_arr[b].
// K1b (blocks NCB..NCB+NOB-1): out1[i] = Kw[i, 0:Q] . q  (independent stream)
// ---------------------------------------------------------------------------
__global__ __launch_bounds__(256) void k1_kernel(
    const float* __restrict__ qvec, const float* __restrict__ ctx,
    const float* __restrict__ Kw,
    float* __restrict__ partial, float* __restrict__ m_arr,
    float* __restrict__ Z_arr, float* __restrict__ out1)
{
    const int tid  = threadIdx.x;
    const int lane = tid & 63;
    const int wid  = tid >> 6;

    if (blockIdx.x < NCB) {
        const float4* __restrict__ qv = (const float4*)qvec;
        float4 qr[4];
        #pragma unroll
        for (int k = 0; k < 4; ++k) qr[k] = qv[tid + k * 256];

        float4 acc[4];
        #pragma unroll
        for (int k = 0; k < 4; ++k) acc[k] = make_float4(0.f, 0.f, 0.f, 0.f);
        float m = -3.4e38f, Z = 0.f;

        __shared__ float red[4];
        const int r0 = blockIdx.x * RPB;

        for (int r = 0; r < RPB; ++r) {
            const float4* __restrict__ row = (const float4*)(ctx + (size_t)(r0 + r) * Q);
            float4 v[4];
            #pragma unroll
            for (int k = 0; k < 4; ++k) v[k] = row[tid + k * 256];

            float d = 0.f;
            #pragma unroll
            for (int k = 0; k < 4; ++k) {
                d = fmaf(v[k].x, qr[k].x, d);
                d = fmaf(v[k].y, qr[k].y, d);
                d = fmaf(v[k].z, qr[k].z, d);
                d = fmaf(v[k].w, qr[k].w, d);
            }
            #pragma unroll
            for (int off = 32; off > 0; off >>= 1) d += __shfl_down(d, off, 64);
            if (lane == 0) red[wid] = d;
            __syncthreads();
            const float s = red[0] + red[1] + red[2] + red[3];
            __syncthreads();

            if (s > m) {                         // block-uniform branch
                const float scale = __expf(m - s);   // first row: exp(-huge)=0
                Z *= scale;
                #pragma unroll
                for (int k = 0; k < 4; ++k) {
                    acc[k].x *= scale; acc[k].y *= scale;
                    acc[k].z *= scale; acc[k].w *= scale;
                }
                m = s;
            }
            const float w = __expf(s - m);
            Z += w;
            #pragma unroll
            for (int k = 0; k < 4; ++k) {
                acc[k].x = fmaf(w, v[k].x, acc[k].x);
                acc[k].y = fmaf(w, v[k].y, acc[k].y);
                acc[k].z = fmaf(w, v[k].z, acc[k].z);
                acc[k].w = fmaf(w, v[k].w, acc[k].w);
            }
        }

        float4* __restrict__ pb = (float4*)(partial + (size_t)blockIdx.x * Q);
        #pragma unroll
        for (int k = 0; k < 4; ++k) pb[tid + k * 256] = acc[k];
        if (tid == 0) { m_arr[blockIdx.x] = m; Z_arr[blockIdx.x] = Z; }
    } else {
        // ---- out1 = Kw[:, 0:Q] . q, one wave per row, 4 rows per wave ----
        const int b = blockIdx.x - NCB;
        const float4* __restrict__ qv = (const float4*)qvec;
        for (int rr = 0; rr < 4; ++rr) {
            const int i = (b * 4 + wid) + rr * 1024;
            const float4* __restrict__ row = (const float4*)(Kw + (size_t)i * (2 * Q));
            float a = 0.f;
            #pragma unroll 4
            for (int it = 0; it < 16; ++it) {
                const int idx = it * 64 + lane;
                float4 x = row[idx], y = qv[idx];
                a = fmaf(x.x, y.x, a); a = fmaf(x.y, y.y, a);
                a = fmaf(x.z, y.z, a); a = fmaf(x.w, y.w, a);
            }
            #pragma unroll
            for (int off = 32; off > 0; off >>= 1) a += __shfl_down(a, off, 64);
            if (lane == 0) out1[i] = a;
        }
    }
}

// ---------------------------------------------------------------------------
// K2: merge the NCB partials:  s_t[j] = (1/Z_tot) * sum_b exp(m_b - M) * p_b[j]
//     64 blocks; each block owns 16 float4 columns; 16 b-groups sweep NCB.
// ---------------------------------------------------------------------------
__global__ __launch_bounds__(256) void k2_kernel(
    const float* __restrict__ partial, const float* __restrict__ m_arr,
    const float* __restrict__ Z_arr, float* __restrict__ s_t)
{
    __shared__ float w_s[NCB];          // 4 KB
    __shared__ float redm[4];
    __shared__ float4 sacc[16][16];     // 4 KB
    const int tid  = threadIdx.x;
    const int lane = tid & 63;
    const int wid  = tid >> 6;

    // M = max_b m_b
    float lm = -3.4e38f;
    for (int b = tid; b < NCB; b += 256) lm = fmaxf(lm, m_arr[b]);
    #pragma unroll
    for (int off = 32; off > 0; off >>= 1) lm = fmaxf(lm, __shfl_down(lm, off, 64));
    if (lane == 0) redm[wid] = lm;
    __syncthreads();
    const float M = fmaxf(fmaxf(redm[0], redm[1]), fmaxf(redm[2], redm[3]));
    __syncthreads();

    // w_b and Z_tot
    float lz = 0.f;
    for (int b = tid; b < NCB; b += 256) {
        const float w = __expf(m_arr[b] - M);
        w_s[b] = w;
        lz = fmaf(w, Z_arr[b], lz);
    }
    #pragma unroll
    for (int off = 32; off > 0; off >>= 1) lz += __shfl_down(lz, off, 64);
    if (lane == 0) redm[wid] = lz;
    __syncthreads();
    const float invZ = 1.f / (redm[0] + redm[1] + redm[2] + redm[3]);

    // weighted column sums
    const int cidx = tid & 15;               // column within block
    const int g    = tid >> 4;               // 0..15 b-group
    const int c4   = blockIdx.x * 16 + cidx; // global float4 column
    const float4* __restrict__ p = (const float4*)partial;
    float4 acc = make_float4(0.f, 0.f, 0.f, 0.f);
    for (int b = g; b < NCB; b += 16) {
        const float w = w_s[b];
        float4 v = p[(size_t)b * (Q / 4) + c4];
        acc.x = fmaf(w, v.x, acc.x); acc.y = fmaf(w, v.y, acc.y);
        acc.z = fmaf(w, v.z, acc.z); acc.w = fmaf(w, v.w, acc.w);
    }
    sacc[g][cidx] = acc;
    __syncthreads();
    if (g == 0) {
        float4 t = sacc[0][cidx];
        #pragma unroll
        for (int gg = 1; gg < 16; ++gg) {
            float4 u = sacc[gg][cidx];
            t.x += u.x; t.y += u.y; t.z += u.z; t.w += u.w;
        }
        t.x *= invZ; t.y *= invZ; t.z *= invZ; t.w *= invZ;
        ((float4*)s_t)[c4] = t;
    }
}

// ---------------------------------------------------------------------------
// K3: out[i] = out1[i] + Kw[i, Q:2Q] . s_t    (one wave per row)
// ---------------------------------------------------------------------------
__global__ __launch_bounds__(256) void k3_kernel(
    const float* __restrict__ Kw, const float* __restrict__ s_t,
    const float* __restrict__ out1, float* __restrict__ out)
{
    const int lane = threadIdx.x & 63;
    const int wid  = threadIdx.x >> 6;
    const int i = blockIdx.x * 4 + wid;
    const float4* __restrict__ row = (const float4*)(Kw + (size_t)i * (2 * Q) + Q);
    const float4* __restrict__ sv  = (const float4*)s_t;
    float a = 0.f;
    #pragma unroll 4
    for (int it = 0; it < 16; ++it) {
        const int idx = it * 64 + lane;
        float4 x = row[idx], y = sv[idx];
        a = fmaf(x.x, y.x, a); a = fmaf(x.y, y.y, a);
        a = fmaf(x.z, y.z, a); a = fmaf(x.w, y.w, a);
    }
    #pragma unroll
    for (int off = 32; off > 0; off >>= 1) a += __shfl_down(a, off, 64);
    if (lane == 0) out[i] = out1[i] + a;
}

// ---------------------------------------------------------------------------
extern "C" void kernel_launch(void* const* d_in, const int* in_sizes, int n_in,
                              void* d_out, int out_size, void* d_ws, size_t ws_size,
                              hipStream_t stream)
{
    const float* query = (const float*)d_in[0];   // [Q]
    const float* ctx   = (const float*)d_in[1];   // [L, Q]
    const float* Kw    = (const float*)d_in[2];   // [Q, 2Q]
    float* out = (float*)d_out;                   // [Q]

    // workspace layout (floats)
    float* ws      = (float*)d_ws;
    float* m_arr   = ws;                          // NCB   = 1024
    float* Z_arr   = ws + NCB;                    // NCB   = 1024
    float* out1    = ws + 2 * NCB;                // Q     = 4096
    float* s_t     = ws + 2 * NCB + Q;            // Q     = 4096
    float* partial = ws + 2 * NCB + 2 * Q;        // NCB*Q = 16 MiB/4

    k1_kernel<<<NCB + NOB, 256, 0, stream>>>(query, ctx, Kw,
                                             partial, m_arr, Z_arr, out1);
    k2_kernel<<<Q / 4 / 16, 256, 0, stream>>>(partial, m_arr, Z_arr, s_t);
    k3_kernel<<<Q / 4, 256, 0, stream>>>(Kw, s_t, out1, out);
}